// Round 6
// baseline (433.178 us; speedup 1.0000x reference)
//
#include <hip/hip_runtime.h>

static constexpr int S_TOT = 1024 * 1024;  // flattened image size
static constexpr int RK = 4;               // rank
static constexpr int NK = 3;               // k = 1..3 contribute to d
static constexpr int NB1 = 1024;           // blocks in dots_partial
static constexpr int NCOMP = NK * RK;      // 12 partial components

// Kernel 1: per-block partials of d[k][r] = dot(z, W[k+1][:, r]).
// No atomics: block b stores its 12 partials at part[c*NB1 + b].
__global__ __launch_bounds__(256) void dots_partial(
    const float* __restrict__ z,
    const float* __restrict__ W,      // (20, S, 4) flat; we use k=1..3
    float* __restrict__ part) {       // (12, NB1) column-contiguous
  float acc[NK][RK];
#pragma unroll
  for (int k = 0; k < NK; ++k)
#pragma unroll
    for (int r = 0; r < RK; ++r) acc[k][r] = 0.f;

  const int tid = blockIdx.x * blockDim.x + threadIdx.x;
  const int stride = gridDim.x * blockDim.x;
  for (int s = tid; s < S_TOT; s += stride) {
    const float zs = z[s];
#pragma unroll
    for (int k = 0; k < NK; ++k) {
      const float4 w = *reinterpret_cast<const float4*>(
          W + (size_t)(k + 1) * S_TOT * RK + (size_t)s * RK);
      acc[k][0] = fmaf(zs, w.x, acc[k][0]);
      acc[k][1] = fmaf(zs, w.y, acc[k][1]);
      acc[k][2] = fmaf(zs, w.z, acc[k][2]);
      acc[k][3] = fmaf(zs, w.w, acc[k][3]);
    }
  }

  // 64-lane butterfly reduce each of the 12 partials
#pragma unroll
  for (int k = 0; k < NK; ++k)
#pragma unroll
    for (int r = 0; r < RK; ++r) {
      float v = acc[k][r];
#pragma unroll
      for (int off = 32; off > 0; off >>= 1) v += __shfl_xor(v, off, 64);
      acc[k][r] = v;
    }

  __shared__ float lds[4][NCOMP];  // 4 waves per 256-thread block
  const int wave = threadIdx.x >> 6;
  const int lane = threadIdx.x & 63;
  if (lane == 0) {
#pragma unroll
    for (int k = 0; k < NK; ++k)
#pragma unroll
      for (int r = 0; r < RK; ++r) lds[wave][k * RK + r] = acc[k][r];
  }
  __syncthreads();
  if (threadIdx.x < NCOMP) {
    float v = 0.f;
#pragma unroll
    for (int w = 0; w < 4; ++w) v += lds[w][threadIdx.x];
    part[threadIdx.x * NB1 + blockIdx.x] = v;  // plain store, no atomic
  }
}

// Kernel 2: one wave folds (12, NB1) partials -> coef[4].
__global__ __launch_bounds__(64) void reduce_coef(
    const float* __restrict__ part,   // (12, NB1)
    float* __restrict__ coef) {       // 4 floats
  const int lane = threadIdx.x;
  float d[NCOMP];
#pragma unroll
  for (int c = 0; c < NCOMP; ++c) {
    float v = 0.f;
    for (int i = lane; i < NB1; i += 64) v += part[c * NB1 + i];
#pragma unroll
    for (int off = 32; off > 0; off >>= 1) v += __shfl_xor(v, off, 64);
    d[c] = v;  // every lane now holds the full sum
  }
  if (lane < RK) {
    const float d0 = d[lane];
    const float d1 = d[RK + lane];
    const float d2 = d[2 * RK + lane];
    const float c1 = d0;
    const float c2 = c1 * d1;
    const float c3 = c2 * d2;
    coef[lane] = 2.f + c1 + c2 + c3;
  }
}

// Kernel 3: out[s] = W0[s,:]·coef + b[s]
__global__ __launch_bounds__(256) void out_kernel(
    const float* __restrict__ W0,    // (S, 4), k=0 slice of W
    const float* __restrict__ b,
    const float* __restrict__ coefg, // 4 floats from kernel 2
    float* __restrict__ out) {
  __shared__ float coef[RK];
  if (threadIdx.x < RK) coef[threadIdx.x] = coefg[threadIdx.x];
  __syncthreads();
  const float c0 = coef[0], c1 = coef[1], c2 = coef[2], c3 = coef[3];

  const int s = blockIdx.x * blockDim.x + threadIdx.x;  // one row per thread
  if (s >= S_TOT) return;
  const float4 w = *reinterpret_cast<const float4*>(W0 + (size_t)s * RK);
  const float bs = b[s];
  out[s] = fmaf(w.x, c0, fmaf(w.y, c1, fmaf(w.z, c2, fmaf(w.w, c3, bs))));
}

extern "C" void kernel_launch(void* const* d_in, const int* in_sizes, int n_in,
                              void* d_out, int out_size, void* d_ws, size_t ws_size,
                              hipStream_t stream) {
  const float* z = (const float*)d_in[0];
  const float* W = (const float*)d_in[1];  // (20, S, 4)
  const float* b = (const float*)d_in[2];
  float* out = (float*)d_out;

  float* part = (float*)d_ws;                  // 12 * NB1 floats
  float* coef = part + NCOMP * NB1;            // 4 floats

  dots_partial<<<NB1, 256, 0, stream>>>(z, W, part);
  reduce_coef<<<1, 64, 0, stream>>>(part, coef);

  const int threads = 256;
  const int blocks = (S_TOT + threads - 1) / threads;  // 4096
  out_kernel<<<blocks, threads, 0, stream>>>(W /*k=0 slice*/, b, coef, out);
}